// Round 9
// baseline (118.886 us; speedup 1.0000x reference)
//
#include <hip/hip_runtime.h>
#include <math.h>

#define NUM_A 90
#define RBINS 727      // 2*363 + 1
#define HDIM  256
#define WDIM  256
#define RMIN  181      // lowest bin ever touched
#define RACT  365      // active bins: 181..545
#define TPB   768      // 368 bins x 2 strips (+pad) = 12 waves
#define PH_ROWS 60
#define ROWSTR  264    // floats per row slot: 4 zero | 256 image | 4 zero
#define GPAD    16
#define TILE_N  (GPAD + PH_ROWS * ROWSTR + GPAD)   // 15872 floats = 63488 B

typedef float f2 __attribute__((ext_vector_type(2)));

static __device__ __forceinline__ f2 fma2(f2 a, f2 b, f2 c) {
#if __has_builtin(__builtin_elementwise_fma)
    return __builtin_elementwise_fma(a, b, c);
#else
    return f2{fmaf(a.x, b.x, c.x), fmaf(a.y, b.y, c.y)};
#endif
}
static __device__ __forceinline__ f2 max2(f2 a, f2 b) {
#if __has_builtin(__builtin_elementwise_max)
    return __builtin_elementwise_max(a, b);
#else
    return f2{fmaxf(a.x, b.x), fmaxf(a.y, b.y)};
#endif
}
static __device__ __forceinline__ f2 ceil2(f2 a) {
#if __has_builtin(__builtin_elementwise_ceil)
    return __builtin_elementwise_ceil(a);
#else
    return f2{ceilf(a.x), ceilf(a.y)};
#endif
}

// ---------------- angle table: tab[2a]=cos, tab[2a+1]=sin ----------------
__global__ void angles_k(float* __restrict__ tab) {
    int a = threadIdx.x;
    if (a < NUM_A) {
        double th = (double)a * (3.14159265358979323846 / 90.0);
        tab[2 * a]     = (float)cos(th);
        tab[2 * a + 1] = (float)sin(th);
    }
}

// ---------------- transpose: maskT[b][x][y] = mask[b][y][x] ----------------
__global__ __launch_bounds__(256) void transpose_k(const float* __restrict__ in,
                                                   float* __restrict__ out) {
    __shared__ float tile[32][33];
    int b = blockIdx.z;
    const float* ib = in  + (size_t)b * (HDIM * WDIM);
    float*       ob = out + (size_t)b * (HDIM * WDIM);
    int x0 = blockIdx.x * 32, y0 = blockIdx.y * 32;
    int tx = threadIdx.x, ty = threadIdx.y;
#pragma unroll
    for (int j = ty; j < 32; j += 8)
        tile[j][tx] = ib[(size_t)(y0 + j) * WDIM + (x0 + tx)];
    __syncthreads();
#pragma unroll
    for (int j = ty; j < 32; j += 8)
        ob[(size_t)(x0 + j) * HDIM + (y0 + tx)] = tile[tx][j];
}

// ---------------- per-phase accumulation, sign-specialized ----------------
// Taps: i0 = ceil(lo) [POS] or ceil(lo)-1 [NEG, folded into LO0]; walks
// +1 [POS] / -1 [NEG]. u0 in (-1,-1+ca] always (algebraic identity), so
// w0 = 1+u0, w1 = 1-|u1| need no clamps; w2 = max(0, 1-u2). Strays read
// zeroed pads -> weight value irrelevant. Rows paired as float2 (VOP3P).
template<bool POS>
static __device__ __forceinline__ void phase_accum(
    const float* __restrict__ tile, int jsp, int jep, int phb,
    float LO0, float dlo, float Z0, float cj, float ci, float ca, f2& accv)
{
    const f2 civ  = {ci, ci};
    const f2 cav  = {ca, ca};
    const f2 ca2v = {ca + ca, ca + ca};
    const f2 dlo2v = {dlo + dlo, dlo + dlo};
    const f2 cj2v  = {cj + cj, cj + cj};
    const f2 onev  = {1.0f, 1.0f};
    const f2 zerov = {0.0f, 0.0f};
    const int IB = POS ? 0 : -2;

    int j   = jsp;
    int fiB = (jsp - phb) * ROWSTR + (GPAD + 4 + IB);
    int n4  = (jep - jsp) & ~3;
    for (int e = 0; e < n4; e += 4, j += 4, fiB += 4 * ROWSTR) {
        float jf  = (float)j;
        float loa = fmaf(jf, dlo, LO0);
        float za  = fmaf(jf, cj, Z0);
        f2 loA = {loa, loa + dlo};
        f2 zA  = {za, za + cj};
        f2 loB = loA + dlo2v;
        f2 zB  = zA + cj2v;
        f2 f0A = ceil2(loA), f0B = ceil2(loB);
        int i0 = (int)f0A.x, i1 = (int)f0A.y, i2 = (int)f0B.x, i3 = (int)f0B.y;
        int a0 = fiB + i0;
        int a1 = fiB + ROWSTR + i1;
        int a2 = fiB + 2 * ROWSTR + i2;
        int a3 = fiB + 3 * ROWSTR + i3;
        float v00 = tile[a0], v01 = tile[a0 + 1], v02 = tile[a0 + 2];
        float v10 = tile[a1], v11 = tile[a1 + 1], v12 = tile[a1 + 2];
        float v20 = tile[a2], v21 = tile[a2 + 1], v22 = tile[a2 + 2];
        float v30 = tile[a3], v31 = tile[a3 + 1], v32 = tile[a3 + 2];

        f2 u0A = fma2(f0A, civ, zA);
        f2 u0B = fma2(f0B, civ, zB);
        f2 u1A = u0A + cav, u2A = u0A + ca2v;
        f2 u1B = u0B + cav, u2B = u0B + ca2v;
        f2 m0A, m1A, m2A, m0B, m1B, m2B;
        if (POS) {
            m0A = {v00, v10}; m1A = {v01, v11}; m2A = {v02, v12};
            m0B = {v20, v30}; m1B = {v21, v31}; m2B = {v22, v32};
        } else {
            m0A = {v02, v12}; m1A = {v01, v11}; m2A = {v00, v10};
            m0B = {v22, v32}; m1B = {v21, v31}; m2B = {v20, v30};
        }
        accv = accv + (m0A + m1A);
        accv = fma2(m0A, u0A, accv);
        accv = fma2(m1A, -max2(u1A, -u1A), accv);
        accv = fma2(m2A, max2(onev - u2A, zerov), accv);
        accv = accv + (m0B + m1B);
        accv = fma2(m0B, u0B, accv);
        accv = fma2(m1B, -max2(u1B, -u1B), accv);
        accv = fma2(m2B, max2(onev - u2B, zerov), accv);
    }
    for (; j < jep; ++j, fiB += ROWSTR) {   // tail: <=3 rows
        float jf = (float)j;
        float lo = fmaf(jf, dlo, LO0);
        float z  = fmaf(jf, cj, Z0);
        float f0 = ceilf(lo);
        int   i0 = (int)f0;
        int   a0 = fiB + i0;
        float v0 = tile[a0], v1 = tile[a0 + 1], v2 = tile[a0 + 2];
        float m0 = POS ? v0 : v2, m1 = v1, m2 = POS ? v2 : v0;
        float u0 = fmaf(f0, ci, z);
        float u1 = u0 + ca, u2 = u0 + ca + ca;
        accv.x += (m0 + m1);
        accv.x = fmaf(m0, u0, accv.x);
        accv.x = fmaf(m1, -fabsf(u1), accv.x);
        accv.x = fmaf(m2, fmaxf(1.0f - u2, 0.0f), accv.x);
    }
}

// ---------------- LDS-staged gather hough, padded tile ----------------
__global__ __launch_bounds__(TPB, 6) void hough_lds_k(const float* __restrict__ srcA,
                                                      const float* __restrict__ srcB,
                                                      const float* __restrict__ tab,
                                                      float* __restrict__ out) {
    __shared__ float tile[TILE_N];
    int ba = blockIdx.x;
    int b  = ba / NUM_A;
    int a  = ba - b * NUM_A;

    float c = tab[2 * a], s = tab[2 * a + 1];
    bool  xs = fabsf(c) >= fabsf(s);       // solve axis = larger coeff
    float ci = xs ? c : s;
    float cj = xs ? s : c;
    const float* src = (xs ? srcA : srcB) + (size_t)b * (HDIM * WDIM);

    int tid = threadIdx.x;
    // zero the pads once; staging never overwrites them
    if (tid < 512) {
        int idx;
        if (tid < 480) {
            int sl = tid >> 3, o = tid & 7;
            idx = GPAD + sl * ROWSTR + (o < 4 ? o : 256 + o);
        } else {
            int q = tid - 480;
            idx = (q < 16) ? q : (GPAD + PH_ROWS * ROWSTR + q - 16);
        }
        tile[idx] = 0.0f;
    }

    int   bin = tid >> 1;                  // 2 strips
    int   m   = tid & 1;
    int   r   = RMIN + bin;
    float rf  = (float)r;
    bool  active = bin < RACT;

    // active j-range (R8-proven): rows whose in-image t-span hits (r-1,r+1)
    float p = fminf(-128.0f * ci, 127.0f * ci);
    float q = fmaxf(-128.0f * ci, 127.0f * ci);
    int jl, jh;
    float acj = fabsf(cj);
    if (acj > 1e-5f) {
        float invj = 1.0f / cj;
        float jA = (rf + 1.0f - p - 363.0f) * invj + 128.0f;
        float jB = (rf - 1.0f - q - 363.0f) * invj + 128.0f;
        float jmn = fminf(jA, jB) - 1.0f;   // widen: zero pads self-guard strays
        float jmx = fmaxf(jA, jB) + 2.0f;
        jl = (int)fminf(fmaxf(jmn, 0.0f), 256.0f);
        jh = (int)fminf(fmaxf(jmx, 0.0f), 256.0f);
    } else {                               // cj ~ 0: t j-independent
        bool any = (363.0f + q > rf - 1.01f) && (363.0f + p < rf + 1.01f);
        jl = 0; jh = any ? 256 : 0;
    }
    if (!active) { jl = 0; jh = 0; }
    int len = jh - jl;
    int ls = jl + ((m * len) >> 1);        // exact strip partition
    int le = jl + (((m + 1) * len) >> 1);

    float inv = 1.0f / ci;                 // |ci| >= 0.707
    bool  pos = ci > 0.0f;
    float ca  = fabsf(ci);
    float Z0  = 363.0f - rf - 128.0f * cj - 128.0f * ci;
    float LO0 = (-1.0f - Z0) * inv - (pos ? 0.0f : 1.0f);  // ceil(x)-1 = ceil(x-1)
    float dlo = -cj * inv;                 // |dlo| <= 1

    f2 accv = {0.0f, 0.0f};
    int wid = tid >> 6, lane = tid & 63;
    for (int ph = 0; ph < 5; ++ph) {
        int phb   = ph * PH_ROWS;
        int nrows = (phb + PH_ROWS <= 256) ? PH_ROWS : (256 - phb);
        if (ph) __syncthreads();           // prior-phase LDS reads complete
        // stage: one wave stages one 256-float row interior (64 x 16B)
        for (int sl = wid; sl < nrows; sl += 12) {
            const float* grow = src + (size_t)(phb + sl) * 256 + lane * 4;
            float* lrow = tile + (GPAD + sl * ROWSTR + 4) + lane * 4;
            __builtin_amdgcn_global_load_lds(
                (const __attribute__((address_space(1))) unsigned int*)grow,
                (__attribute__((address_space(3))) unsigned int*)lrow, 16, 0, 0);
        }
        __syncthreads();                   // staging (and pad zeroing) complete

        int jsp = ls > phb ? ls : phb;
        int jep = le < phb + nrows ? le : phb + nrows;
        if (jep <= jsp) continue;
        if (pos) phase_accum<true >(tile, jsp, jep, phb, LO0, dlo, Z0, cj, ci, ca, accv);
        else     phase_accum<false>(tile, jsp, jep, phb, LO0, dlo, Z0, cj, ci, ca, accv);
    }

    float acc = accv.x + accv.y;
    acc += __shfl_xor(acc, 1);             // reduce the 2 strips
    if (active && m == 0)
        out[(size_t)ba * RBINS + r] = acc;
}

// ---------------- fallback (no workspace): R7-proven global-gather ----------------
typedef float f3v __attribute__((ext_vector_type(3)));
typedef f3v __attribute__((aligned(4))) f3u;
#define FB_GRP (368 * 4)

__global__ __launch_bounds__(256) void hough_fb_k(const float* __restrict__ src0,
                                                  float* __restrict__ out, int nba) {
    int gtid = blockIdx.x * 256 + threadIdx.x;
    int grp  = gtid / FB_GRP;
    if (grp >= nba) return;
    int k    = gtid - grp * FB_GRP;
    int ba   = __builtin_amdgcn_readfirstlane(grp);
    int b    = ba / NUM_A;
    int a    = ba - b * NUM_A;
    double th = (double)a * (3.14159265358979323846 / 90.0);
    float c = (float)cos(th), s = (float)sin(th);
    bool  xs = fabsf(c) >= fabsf(s);
    float ci = xs ? c : s, cj = xs ? s : c;
    const float* src = src0 + (size_t)b * (HDIM * WDIM);
    int   bin = k >> 2, m = k & 3;
    int   r = RMIN + bin;
    float rf = (float)r;
    bool  active = bin < RACT;
    float inv = 1.0f / ci, ainv = fabsf(inv);
    float p = fminf(-128.0f * ci, 127.0f * ci);
    float q = fmaxf(-128.0f * ci, 127.0f * ci);
    int jl, jh;
    float acj = fabsf(cj);
    if (acj > 1e-5f) {
        float invj = 1.0f / cj;
        float jA = (rf + 1.0f - p - 363.0f) * invj + 128.0f;
        float jB = (rf - 1.0f - q - 363.0f) * invj + 128.0f;
        jl = (int)fminf(fmaxf(fminf(jA, jB) - 1.0f, 0.0f), 256.0f);
        jh = (int)fminf(fmaxf(fmaxf(jA, jB) + 2.0f, 0.0f), 256.0f);
    } else {
        bool any = (363.0f + q > rf - 1.01f) && (363.0f + p < rf + 1.01f);
        jl = 0; jh = any ? 256 : 0;
    }
    if (!active) { jl = 0; jh = 0; }
    int len = jh - jl;
    int js = jl + ((m * len) >> 2);
    int je = jl + (((m + 1) * len) >> 2);
    float dlo = -cj * inv;
    float LO0 = 128.0f + (rf - 363.0f) * inv - ainv + 128.0f * cj * inv;
    float Z0  = 363.0f - rf - 128.0f * cj - 128.0f * ci;
    float ci2 = ci + ci;
    float acc = 0.0f;
    for (int j = js; j < je; ++j) {
        float jf  = (float)j;
        float lo0 = fmaf(jf, dlo, LO0);
        float z0  = fmaf(jf, cj, Z0);
        float f0  = __builtin_amdgcn_fmed3f(ceilf(lo0), 0.0f, 253.0f);
        int   i0  = (int)f0;
        float a0, b0, c0;
        if (xs) {
            f3v mm = *(const f3u*)(src + ((size_t)j << 8) + i0);
            a0 = mm.x; b0 = mm.y; c0 = mm.z;
        } else {
            const float* p0 = src + j + ((size_t)i0 << 8);
            a0 = p0[0]; b0 = p0[256]; c0 = p0[512];
        }
        float u0 = fmaf(f0, ci, z0);
        acc = fmaf(a0, fmaxf(1.0f - fabsf(u0), 0.0f), acc);
        acc = fmaf(b0, fmaxf(1.0f - fabsf(u0 + ci), 0.0f), acc);
        acc = fmaf(c0, fmaxf(1.0f - fabsf(u0 + ci2), 0.0f), acc);
    }
    acc += __shfl_xor(acc, 1);
    acc += __shfl_xor(acc, 2);
    if (active && m == 0)
        out[(size_t)ba * RBINS + r] = acc;
}

extern "C" void kernel_launch(void* const* d_in, const int* in_sizes, int n_in,
                              void* d_out, int out_size, void* d_ws, size_t ws_size,
                              hipStream_t stream) {
    const float* mask = (const float*)d_in[0];
    float* out = (float*)d_out;
    int B = in_sizes[0] / (HDIM * WDIM);   // 16
    int nba = B * NUM_A;

    size_t needT = (size_t)B * HDIM * WDIM * sizeof(float);
    size_t needW = needT + 2 * NUM_A * sizeof(float);
    int fast = (d_ws != nullptr && ws_size >= needW) ? 1 : 0;
    float* maskT = (float*)d_ws;
    float* tab   = (float*)((char*)d_ws + needT);

    // zero the never-touched rho bins once per call (also covers len==0 bins)
    hipMemsetAsync(d_out, 0, (size_t)out_size * sizeof(float), stream);

    if (fast) {
        transpose_k<<<dim3(WDIM / 32, HDIM / 32, B), dim3(32, 8), 0, stream>>>(mask, maskT);
        angles_k<<<1, 128, 0, stream>>>(tab);
        hough_lds_k<<<nba, TPB, 0, stream>>>(mask, maskT, tab, out);
    } else {
        int nthreads = nba * FB_GRP;
        hough_fb_k<<<(nthreads + 255) / 256, 256, 0, stream>>>(mask, out, nba);
    }
}